// Round 14
// baseline (23.880 us; speedup 1.0000x reference)
//
#include <hip/hip_runtime.h>

// DiscreteLinear: z[b,i] = sum_j weight[a[b],i,j] * x[b,j] + bias[a[b],i]
// B=2048, A=64, D=512.
// R13: ablate the in-block bucket prologue. R7-R12: all K-loop schedule
// variants null; only 2 blocks/CU (+0.4us) helped. Last unisolated serial
// phase: every block scanning all 2048 act entries (~1-2us with HBM idle,
// chip-synchronized at t=0). Split: tiny 1-block bucket kernel (d_ws:
// counts/offsets/ushort perm) + GEMM whose prologue is ONE 1KB
// global_load_lds of its perm slice (oldest VMEM op -> vmcnt(6) retires
// it under the W burst). W-ring/K-loop/staging byte-identical to R12.

#define NA 64
#define DD 512
#define NB 2048
#define BN 64           // output cols per block
#define NW 4            // waves per block
#define MT 48           // m-tile rows
#define BK 32           // fp32 k per ring step
#define NSTEPS 16       // DD / BK
#define NSLOT 3         // ring slots

typedef __bf16  bf16x8  __attribute__((ext_vector_type(8)));
typedef __bf16  bf16x4  __attribute__((ext_vector_type(4)));
typedef float   floatx4 __attribute__((ext_vector_type(4)));

#define GLD16(g, l)                                                         \
  __builtin_amdgcn_global_load_lds(                                         \
      (const __attribute__((address_space(1))) void*)(g),                   \
      (__attribute__((address_space(3))) void*)(l), 16, 0, 0)
#define VMCNT(n) asm volatile("s_waitcnt vmcnt(" #n ")" ::: "memory")
#define LGKMCNT0 asm volatile("s_waitcnt lgkmcnt(0)" ::: "memory")
#define SBAR     __builtin_amdgcn_s_barrier()
#define SCHED0   __builtin_amdgcn_sched_barrier(0)

static __device__ inline bf16x8 cvt8(floatx4 lo, floatx4 hi) {
    bf16x8 r;
    r[0] = (__bf16)lo[0]; r[1] = (__bf16)lo[1];
    r[2] = (__bf16)lo[2]; r[3] = (__bf16)lo[3];
    r[4] = (__bf16)hi[0]; r[5] = (__bf16)hi[1];
    r[6] = (__bf16)hi[2]; r[7] = (__bf16)hi[3];
    return r;
}

// Bucket: 1 block, 256 threads. Per-wave hist + shfl-scan + per-wave
// stable scatter (all LDS atomics intra-wave). Proven in R3.
__global__ __launch_bounds__(256) void dl_bucket(const int* __restrict__ act,
                                                 int* __restrict__ counts,
                                                 int* __restrict__ offsets,
                                                 unsigned short* __restrict__ perm) {
    __shared__ int s_hist[4][NA];
    __shared__ int s_cur[4][NA];
    const int t = threadIdx.x;
    const int w = t >> 6;
    ((int*)s_hist)[t] = 0;
    __syncthreads();
    int myact[8];
#pragma unroll
    for (int i = 0; i < 8; ++i) {
        myact[i] = act[t + i * 256];
        atomicAdd(&s_hist[w][myact[i]], 1);
    }
    __syncthreads();
    if (t < NA) {
        const int h0 = s_hist[0][t], h1 = s_hist[1][t];
        const int h2 = s_hist[2][t], h3 = s_hist[3][t];
        const int tot = h0 + h1 + h2 + h3;
        int incl = tot;
#pragma unroll
        for (int d = 1; d < 64; d <<= 1) {
            int up = __shfl_up(incl, d, 64);
            if (t >= d) incl += up;
        }
        const int excl = incl - tot;
        counts[t]  = tot;
        offsets[t] = excl;
        s_cur[0][t] = excl;
        s_cur[1][t] = excl + h0;
        s_cur[2][t] = excl + h0 + h1;
        s_cur[3][t] = excl + h0 + h1 + h2;
    }
    __syncthreads();
#pragma unroll
    for (int i = 0; i < 8; ++i) {
        int pos = atomicAdd(&s_cur[w][myact[i]], 1);
        perm[pos] = (unsigned short)(t + i * 256);
    }
}

// GEMM: grid (64 actions, 8 col-tiles), 256 thr (4 waves), 2 blocks/CU.
__global__ __launch_bounds__(256, 2) void dl_gemm(
        const float* __restrict__ x,
        const float* __restrict__ weight,
        const float* __restrict__ bias,
        const int*   __restrict__ counts,
        const int*   __restrict__ offsets,
        const unsigned short* __restrict__ perm,
        float*       __restrict__ out)
{
    const int a    = blockIdx.x;         // linear id = a + 64*y -> XCD = a%8
    const int tid  = threadIdx.x;
    const int wave = tid >> 6;
    const int lane = tid & 63;
    const int l16  = lane & 15;
    const int kgrp = lane >> 4;
    const int h    = l16 & 7;
    const int colbase = blockIdx.y * BN;
    const int ncol    = colbase + wave * 16 + l16;

    const int cnt = counts[a];           // uniform scalar loads
    if (cnt == 0) return;
    const int base = offsets[a];

    __shared__ __align__(16) __bf16 Xs[MT][DD];        // 48 KB
    __shared__ __align__(16) float  Wl[NSLOT][BN][BK]; // 24 KB ring
    __shared__ __align__(16) unsigned short s_perm[512]; // 1 KB (one GLD16)

    const float* wtile = weight + (size_t)a * DD * DD + (size_t)colbase * DD;

    // DMA geometry (R12-identical): wave owns ring rows [wave*16,+16).
    const int r8 = lane >> 3;             // 0..7 row within call
    const int u8 = lane & 7;              // 0..7 16B unit within 128B slice

    auto issue_step = [&](int slot, int s) {
#pragma unroll
        for (int c = 0; c < 2; ++c)
            GLD16(wtile + (size_t)(wave * 16 + c * 8 + r8) * DD + s * BK
                        + ((u8 ^ r8) << 2),
                  (char*)&Wl[slot][wave * 16 + c * 8][0]);
    };

    const float bias_v = bias[(size_t)a * DD + ncol];
    const int   srow   = tid >> 5;        // x staging: rows 0..7 (+8/pass)
    const int   skk    = (tid & 31) << 2; // 32 lanes x float4 per row

    for (int m0 = 0; m0 < cnt; m0 += MT) {
        const int rem    = min(cnt - m0, MT);
        const int nchunk = (rem + 15) >> 4;               // <= 3

        // ---- (0) perm-slice DMA (OLDEST vm op), then W entry burst ----
        // b0: 16B-aligned, clamped so the 1KB read stays inside perm[2048].
        const int bm = base + m0;
        const int b0 = min(bm & ~7, NB - 512);
        const int d  = bm - b0;           // slice offset in s_perm, d+rem<=512
        GLD16((const char*)perm + 2 * b0 + lane * 16, (char*)s_perm);
        issue_step(0, 0);
        issue_step(1, 1);
        issue_step(2, 2);                 // per wave: 1 perm + 6 W in flight
        VMCNT(6);                         // perm landed; W burst still flying

        // ---- (1) x loads (addresses from s_perm; clamped, uncond defs) ----
        floatx4 xv[24];
#pragma unroll
        for (int i = 0; i < 6; ++i) {
            const int r  = srow + 8 * i;
            const int rr = (r < rem) ? r : (rem - 1);
            const float* xr = x + (size_t)(int)s_perm[d + rr] * DD;
#pragma unroll
            for (int j = 0; j < 4; ++j)
                xv[i * 4 + j] = *(const floatx4*)(xr + skk + 128 * j);
        }
        // ---- (2) cvt + swizzled Xs write (only live rows) ----
#pragma unroll
        for (int i = 0; i < 6; ++i) {
            const int r = srow + 8 * i;
            if (r < rem) {
                const int rs = (r & 7) << 3;
#pragma unroll
                for (int j = 0; j < 4; ++j) {
                    const int f0 = skk + 128 * j;
                    bf16x4 bv;
#pragma unroll
                    for (int q = 0; q < 4; ++q) bv[q] = (__bf16)xv[i * 4 + j][q];
                    *(bf16x4*)&Xs[r][f0 ^ rs] = bv;
                }
            }
        }
        LGKMCNT0; SBAR;                   // Xs visible to all waves

        // ---- (3) K loop: barrier-free, 3-slot ring, counted vmcnt ----
        floatx4 acc[3] = {{0,0,0,0},{0,0,0,0},{0,0,0,0}};

        auto compute = [&](int slot, int s) {
            const char* wl = (const char*)&Wl[slot][wave * 16 + l16][0];
            const floatx4 blo = *(const floatx4*)(wl + (((2 * kgrp)     ^ h) << 4));
            const floatx4 bhi = *(const floatx4*)(wl + (((2 * kgrp + 1) ^ h) << 4));
            const bf16x8 bfrag = cvt8(blo, bhi);
            const int kb = (s * BK + kgrp * 8) ^ (h << 3);
#pragma unroll
            for (int mc = 0; mc < 3; ++mc) {
                if (mc < nchunk) {
                    const bf16x8 afrag = *(const bf16x8*)&Xs[mc * 16 + l16][kb];
                    acc[mc] = __builtin_amdgcn_mfma_f32_16x16x32_bf16(
                                  afrag, bfrag, acc[mc], 0, 0, 0);
                }
            }
        };

#pragma unroll
        for (int i = 0; i < NSTEPS; ++i) {
            if (i < NSTEPS - 2)       { VMCNT(4); }
            else if (i == NSTEPS - 2) { VMCNT(2); }
            else                      { VMCNT(0); }
            SCHED0;
            compute(i % NSLOT, i);
            if (i + NSLOT < NSTEPS) issue_step(i % NSLOT, i + NSLOT);
        }

        // ---- (4) epilogue: C/D layout col = lane&15, row = kgrp*4 + r ----
#pragma unroll
        for (int mc = 0; mc < 3; ++mc) {
            if (mc < nchunk) {
#pragma unroll
                for (int r = 0; r < 4; ++r) {
                    const int mloc = mc * 16 + kgrp * 4 + r;
                    if (mloc < rem)
                        out[(size_t)(int)s_perm[d + mloc] * DD + ncol] =
                            acc[mc][r] + bias_v;
                }
            }
        }
        LGKMCNT0; SBAR;                   // s_perm/Xs/ring safe to overwrite
    }
}

extern "C" void kernel_launch(void* const* d_in, const int* in_sizes, int n_in,
                              void* d_out, int out_size, void* d_ws, size_t ws_size,
                              hipStream_t stream) {
    const float* x      = (const float*)d_in[0];
    const int*   act    = (const int*)  d_in[1];
    const float* weight = (const float*)d_in[2];
    const float* bias   = (const float*)d_in[3];
    float*       out    = (float*)d_out;

    int*            counts  = (int*)d_ws;               // [64]
    int*            offsets = counts + NA;              // [64]
    unsigned short* perm    = (unsigned short*)(offsets + NA);  // [2048]

    dl_bucket<<<1, 256, 0, stream>>>(act, counts, offsets, perm);
    dl_gemm<<<dim3(NA, DD / BN), 256, 0, stream>>>(x, weight, bias,
                                                   counts, offsets, perm, out);
}

// Round 15
// 18.903 us; speedup vs baseline: 1.2633x; 1.2633x over previous
//
#include <hip/hip_runtime.h>

// DiscreteLinear: z[b,i] = sum_j weight[a[b],i,j] * x[b,j] + bias[a[b],i]
// B=2048, A=64, D=512.
// R14 = REVERT to R12 (session best, 18.86us).
// Ledger: schedule variants (depth/barriers/segments/early-issue) null;
// 2 blocks/CU +0.4us; split bucket kernel -5us (R13, reverted).
// Surviving model: replays are L3-resident; ~100MB CU-ingress at the
// ~6.5TB/s practical ceiling + ~2us launch/bucket = ~19us. Structure:
// fused in-block bucket, x staged once per tile (swizzled bf16 LDS),
// W streamed via per-wave global_load_lds 3-slot ring with counted
// vmcnt (never 0 mid-loop), barrier-free K loop, 2 blocks/CU.

#define NA 64
#define DD 512
#define NB 2048
#define BN 64           // output cols per block
#define NW 4            // waves per block
#define MT 48           // m-tile rows
#define BK 32           // fp32 k per ring step
#define NSTEPS 16       // DD / BK
#define NSLOT 3         // ring slots

typedef __bf16  bf16x8  __attribute__((ext_vector_type(8)));
typedef __bf16  bf16x4  __attribute__((ext_vector_type(4)));
typedef float   floatx4 __attribute__((ext_vector_type(4)));

#define GLD16(g, l)                                                         \
  __builtin_amdgcn_global_load_lds(                                         \
      (const __attribute__((address_space(1))) void*)(g),                   \
      (__attribute__((address_space(3))) void*)(l), 16, 0, 0)
#define VMCNT(n) asm volatile("s_waitcnt vmcnt(" #n ")" ::: "memory")
#define LGKMCNT0 asm volatile("s_waitcnt lgkmcnt(0)" ::: "memory")
#define SBAR     __builtin_amdgcn_s_barrier()
#define SCHED0   __builtin_amdgcn_sched_barrier(0)

static __device__ inline bf16x8 cvt8(floatx4 lo, floatx4 hi) {
    bf16x8 r;
    r[0] = (__bf16)lo[0]; r[1] = (__bf16)lo[1];
    r[2] = (__bf16)lo[2]; r[3] = (__bf16)lo[3];
    r[4] = (__bf16)hi[0]; r[5] = (__bf16)hi[1];
    r[6] = (__bf16)hi[2]; r[7] = (__bf16)hi[3];
    return r;
}

__global__ __launch_bounds__(256, 2) void dl_fused(
        const float* __restrict__ x,
        const int*   __restrict__ act,
        const float* __restrict__ weight,
        const float* __restrict__ bias,
        float*       __restrict__ out)
{
    const int a    = blockIdx.x;         // linear id = a + 64*y -> XCD = a%8:
    const int tid  = threadIdx.x;        // the 8 col-tiles of an action share
    const int wave = tid >> 6;           // an XCD -> x/act L2 reuse
    const int lane = tid & 63;
    const int l16  = lane & 15;
    const int kgrp = lane >> 4;
    const int h    = l16 & 7;
    const int colbase = blockIdx.y * BN;
    const int ncol    = colbase + wave * 16 + l16;

    __shared__ __align__(16) __bf16 Xs[MT][DD];        // 48 KB
    __shared__ __align__(16) float  Wl[NSLOT][BN][BK]; // 24 KB ring
    __shared__ unsigned short s_perm[NB];              // 4 KB
    __shared__ int s_wcnt[NW];

    const float* wtile = weight + (size_t)a * DD * DD + (size_t)colbase * DD;

    // DMA geometry: wave owns ring rows [wave*16,+16) = its own out cols.
    // Call c covers rows wave*16+c*8+r8; 16B unit u8 source-XORed by row&7
    // (rule #21: linear LDS dest + inverse-swizzled global source).
    const int r8 = lane >> 3;             // 0..7 row within call
    const int u8 = lane & 7;              // 0..7 16B unit within 128B slice

    auto issue_step = [&](int slot, int s) {
#pragma unroll
        for (int c = 0; c < 2; ++c)
            GLD16(wtile + (size_t)(wave * 16 + c * 8 + r8) * DD + s * BK
                        + ((u8 ^ r8) << 2),
                  (char*)&Wl[slot][wave * 16 + c * 8][0]);
    };

    // ---- act loads first (oldest vm ops), then entry DMA burst ----
    const int ibase = wave * (NB / NW);               // 512 samples per wave
    int myact[NB / NW / 64];                          // 8, regs
#pragma unroll
    for (int it = 0; it < NB / NW / 64; ++it)
        myact[it] = act[ibase + it * 64 + lane];

    issue_step(0, 0);
    issue_step(1, 1);
    issue_step(2, 2);                                 // 6 DMAs in flight

    // ---- fused bucket (raw barriers: no vmcnt(0) drain) ----
    int wcnt = 0;
#pragma unroll
    for (int it = 0; it < NB / NW / 64; ++it)
        wcnt += (int)__popcll(__ballot(myact[it] == a));
    if (lane == 0) s_wcnt[wave] = wcnt;
    LGKMCNT0; SBAR;
    int cnt = 0, off = 0;
#pragma unroll
    for (int v = 0; v < NW; ++v) {
        const int c = s_wcnt[v];
        if (v < wave) off += c;
        cnt += c;
    }
    if (cnt == 0) { VMCNT(0); return; }   // drain DMAs before LDS dealloc
#pragma unroll
    for (int it = 0; it < NB / NW / 64; ++it) {
        unsigned long long m = __ballot(myact[it] == a);
        if (myact[it] == a) {
            int pos = off + (int)__popcll(m & ((1ull << lane) - 1ull));
            s_perm[pos] = (unsigned short)(ibase + it * 64 + lane);
        }
        off += (int)__popcll(m);
    }
    LGKMCNT0; SBAR;                       // publish s_perm

    const float bias_v = bias[(size_t)a * DD + ncol];
    const int   srow   = tid >> 5;        // x staging: rows 0..7 (+8/pass)
    const int   skk    = (tid & 31) << 2; // 32 lanes x float4 per row

    for (int m0 = 0; m0 < cnt; m0 += MT) {
        if (m0 > 0) {                     // rare 2nd tile: restart ring
            issue_step(0, 0); issue_step(1, 1); issue_step(2, 2);
        }
        const int rem    = min(cnt - m0, MT);
        const int nchunk = (rem + 15) >> 4;               // <= 3

        // ---- x loads (clamped, unconditional defs; 24 float4 in flight) ----
        floatx4 xv[24];
#pragma unroll
        for (int i = 0; i < 6; ++i) {
            const int r  = srow + 8 * i;
            const int rr = (r < rem) ? r : (rem - 1);
            const float* xr = x + (size_t)s_perm[m0 + rr] * DD;
#pragma unroll
            for (int j = 0; j < 4; ++j)
                xv[i * 4 + j] = *(const floatx4*)(xr + skk + 128 * j);
        }
        // ---- cvt + swizzled Xs write (only live rows) ----
#pragma unroll
        for (int i = 0; i < 6; ++i) {
            const int r = srow + 8 * i;
            if (r < rem) {
                const int rs = (r & 7) << 3;
#pragma unroll
                for (int j = 0; j < 4; ++j) {
                    const int f0 = skk + 128 * j;
                    bf16x4 bv;
#pragma unroll
                    for (int q = 0; q < 4; ++q) bv[q] = (__bf16)xv[i * 4 + j][q];
                    *(bf16x4*)&Xs[r][f0 ^ rs] = bv;
                }
            }
        }
        LGKMCNT0; SBAR;                   // Xs visible to all waves

        // ---- K loop: barrier-free, 3-slot ring, per-wave counted vmcnt ----
        floatx4 acc[3] = {{0,0,0,0},{0,0,0,0},{0,0,0,0}};

        auto compute = [&](int slot, int s) {
            const char* wl = (const char*)&Wl[slot][wave * 16 + l16][0];
            const floatx4 blo = *(const floatx4*)(wl + (((2 * kgrp)     ^ h) << 4));
            const floatx4 bhi = *(const floatx4*)(wl + (((2 * kgrp + 1) ^ h) << 4));
            const bf16x8 bfrag = cvt8(blo, bhi);
            const int kb = (s * BK + kgrp * 8) ^ (h << 3);
#pragma unroll
            for (int mc = 0; mc < 3; ++mc) {
                if (mc < nchunk) {
                    const bf16x8 afrag = *(const bf16x8*)&Xs[mc * 16 + l16][kb];
                    acc[mc] = __builtin_amdgcn_mfma_f32_16x16x32_bf16(
                                  afrag, bfrag, acc[mc], 0, 0, 0);
                }
            }
        };

        // steady: wait step i (vmcnt 4 = 2 iters slack), compute, issue i+3
        // into slot i%3 (just consumed; proven-safe issue-after-compute).
#pragma unroll
        for (int i = 0; i < NSTEPS; ++i) {
            if (i < NSTEPS - 2)       { VMCNT(4); }
            else if (i == NSTEPS - 2) { VMCNT(2); }
            else                      { VMCNT(0); }
            SCHED0;
            compute(i % NSLOT, i);
            if (i + NSLOT < NSTEPS) issue_step(i % NSLOT, i + NSLOT);
        }

        // ---- epilogue: C/D layout col = lane&15, row = kgrp*4 + r ----
#pragma unroll
        for (int mc = 0; mc < 3; ++mc) {
            if (mc < nchunk) {
#pragma unroll
                for (int r = 0; r < 4; ++r) {
                    const int mloc = mc * 16 + kgrp * 4 + r;
                    if (mloc < rem)
                        out[(size_t)s_perm[m0 + mloc] * DD + ncol] =
                            acc[mc][r] + bias_v;
                }
            }
        }
        LGKMCNT0; SBAR;                   // Xs/ring safe to reuse next tile
    }
}

extern "C" void kernel_launch(void* const* d_in, const int* in_sizes, int n_in,
                              void* d_out, int out_size, void* d_ws, size_t ws_size,
                              hipStream_t stream) {
    const float* x      = (const float*)d_in[0];
    const int*   act    = (const int*)  d_in[1];
    const float* weight = (const float*)d_in[2];
    const float* bias   = (const float*)d_in[3];
    float*       out    = (float*)d_out;

    dl_fused<<<dim3(NA, DD / BN), 256, 0, stream>>>(x, act, weight, bias, out);
}